// Round 1
// baseline (167.878 us; speedup 1.0000x reference)
//
#include <hip/hip_runtime.h>
#include <math.h>

#define IMG_H 240
#define IMG_W 320
#define NG 512
#define NEAR_P 0.1f
#define FAR_P 100.0f

// sorted SoA field offsets (each field is NG floats)
#define F_PX 0
#define F_PY 1
#define F_IA 2
#define F_IB 3
#define F_IC 4
#define F_OP 5
#define F_CR 6
#define F_CG 7
#define F_CB 8
#define F_Z  9
#define F_XLO 10
#define F_XHI 11
#define F_YLO 12
#define F_YHI 13
#define NFIELD 14

// ---------------- Kernel 1: preprocess + stable descending sort ----------------
// one block, NG threads; each thread handles one gaussian, then rank-sorts.
__global__ void __launch_bounds__(NG)
prep_sort_kernel(const float* __restrict__ means,      // [NG,3]
                 const float* __restrict__ scales,     // [NG,3]
                 const float* __restrict__ rots,       // [NG,4]
                 const float* __restrict__ colors,     // [NG,3]
                 const float* __restrict__ opac,       // [NG]
                 const float* __restrict__ Km,         // [3,3]
                 const float* __restrict__ Tm,         // [4,4]
                 float* __restrict__ ws,               // [NFIELD*NG] sorted SoA
                 float* __restrict__ radii_out)        // [NG]
{
    const int i = threadIdx.x;

    const float fx = Km[0], fy = Km[4], cx = Km[2], cy = Km[5];
    // Rc rows, t
    const float Rc00 = Tm[0],  Rc01 = Tm[1],  Rc02 = Tm[2],  t0 = Tm[3];
    const float Rc10 = Tm[4],  Rc11 = Tm[5],  Rc12 = Tm[6],  t1 = Tm[7];
    const float Rc20 = Tm[8],  Rc21 = Tm[9],  Rc22 = Tm[10], t2 = Tm[11];

    const float mx = means[3*i+0], my = means[3*i+1], mz = means[3*i+2];
    const float xc = Rc00*mx + Rc01*my + Rc02*mz + t0;
    const float yc = Rc10*mx + Rc11*my + Rc12*mz + t1;
    const float zc = Rc20*mx + Rc21*my + Rc22*mz + t2;

    const float zs = (zc == 0.0f) ? 1e-8f : zc;
    const float px = fx * xc / zs + cx;
    const float py = fy * yc / zs + cy;

    // quaternion -> rotmat
    float qw = rots[4*i+0], qx = rots[4*i+1], qy = rots[4*i+2], qz = rots[4*i+3];
    const float qn = sqrtf(qw*qw + qx*qx + qy*qy + qz*qz);
    qw /= qn; qx /= qn; qy /= qn; qz /= qn;
    float R[3][3];
    R[0][0] = 1.0f - 2.0f*(qy*qy + qz*qz);
    R[0][1] = 2.0f*(qx*qy - qw*qz);
    R[0][2] = 2.0f*(qx*qz + qw*qy);
    R[1][0] = 2.0f*(qx*qy + qw*qz);
    R[1][1] = 1.0f - 2.0f*(qx*qx + qz*qz);
    R[1][2] = 2.0f*(qy*qz - qw*qx);
    R[2][0] = 2.0f*(qx*qz - qw*qy);
    R[2][1] = 2.0f*(qy*qz + qw*qx);
    R[2][2] = 1.0f - 2.0f*(qx*qx + qy*qy);

    const float s0 = scales[3*i+0], s1 = scales[3*i+1], s2v = scales[3*i+2];
    const float ss[3] = { s0*s0, s1*s1, s2v*s2v };

    // cov3d M = R diag(ss) R^T
    float M[3][3];
    #pragma unroll
    for (int r = 0; r < 3; ++r)
        #pragma unroll
        for (int c = 0; c < 3; ++c)
            M[r][c] = R[r][0]*ss[0]*R[c][0] + R[r][1]*ss[1]*R[c][1] + R[r][2]*ss[2]*R[c][2];

    // V = Rc M Rc^T
    const float Rcm[3][3] = {{Rc00,Rc01,Rc02},{Rc10,Rc11,Rc12},{Rc20,Rc21,Rc22}};
    float A[3][3];
    #pragma unroll
    for (int r = 0; r < 3; ++r)
        #pragma unroll
        for (int c = 0; c < 3; ++c)
            A[r][c] = Rcm[r][0]*M[0][c] + Rcm[r][1]*M[1][c] + Rcm[r][2]*M[2][c];
    float V[3][3];
    #pragma unroll
    for (int r = 0; r < 3; ++r)
        #pragma unroll
        for (int c = 0; c < 3; ++c)
            V[r][c] = A[r][0]*Rcm[c][0] + A[r][1]*Rcm[c][1] + A[r][2]*Rcm[c][2];

    // J rows
    const float z2 = zs*zs;
    const float j00 = fx / zs, j02 = -fx * xc / z2;
    const float j11 = fy / zs, j12 = -fy * yc / z2;
    // P = J V  (2x3), using J = [[j00,0,j02],[0,j11,j12]]
    float P0[3], P1[3];
    #pragma unroll
    for (int c = 0; c < 3; ++c) {
        P0[c] = j00*V[0][c] + j02*V[2][c];
        P1[c] = j11*V[1][c] + j12*V[2][c];
    }
    const float a = P0[0]*j00 + P0[2]*j02;
    const float b = P0[0]*0.0f + P0[1]*j11 + P0[2]*j12;
    const float c = P1[1]*j11 + P1[2]*j12;

    const float lam_max = 0.5f*(a + c) + sqrtf(fmaxf(0.25f*(a - c)*(a - c) + b*b, 0.0f));
    const float radius = 3.0f * sqrtf(fmaxf(lam_max, 0.0f));

    const bool visible = (zc > NEAR_P) && (zc < FAR_P) &&
                         (px >= 0.0f) && (px < (float)IMG_W) &&
                         (py >= 0.0f) && (py < (float)IMG_H);

    radii_out[i] = visible ? radius : 0.0f;

    // --- stable descending sort by key ---
    __shared__ float skey[NG];
    const float key = visible ? zc : -1e30f;
    skey[i] = key;
    __syncthreads();
    int rank = 0;
    #pragma unroll 8
    for (int j = 0; j < NG; ++j) {
        const float kj = skey[j];
        rank += (kj > key) || (kj == key && j < i);
    }

    // inverse 2d cov (with eps)
    const float eps = 1e-6f;
    const float ae = a + eps, ce = c + eps;
    const float det = ae*ce - b*b;
    const float ia = ce / det;
    const float ib = -b / det;
    const float ic = ae / det;

    // box bounds
    const float cxp = floorf(px), cyp = floorf(py);
    const float r_int = floorf(radius) + 1.0f;

    float* wpx  = ws + F_PX*NG;
    float* wpy  = ws + F_PY*NG;
    float* wia  = ws + F_IA*NG;
    float* wib  = ws + F_IB*NG;
    float* wic  = ws + F_IC*NG;
    float* wop  = ws + F_OP*NG;
    float* wcr  = ws + F_CR*NG;
    float* wcg  = ws + F_CG*NG;
    float* wcb  = ws + F_CB*NG;
    float* wz   = ws + F_Z*NG;
    float* wxlo = ws + F_XLO*NG;
    float* wxhi = ws + F_XHI*NG;
    float* wylo = ws + F_YLO*NG;
    float* wyhi = ws + F_YHI*NG;

    wpx[rank] = px;
    wpy[rank] = py;
    wia[rank] = ia;
    wib[rank] = ib;
    wic[rank] = ic;
    wop[rank] = opac[i];
    wcr[rank] = colors[3*i+0];
    wcg[rank] = colors[3*i+1];
    wcb[rank] = colors[3*i+2];
    wz [rank] = zc;
    if (visible) {
        wxlo[rank] = cxp - r_int;
        wxhi[rank] = cxp + r_int;
        wylo[rank] = cyp - r_int;
        wyhi[rank] = cyp + r_int;
    } else {
        // empty box -> alpha stays 0 for this gaussian everywhere
        wxlo[rank] = 1e30f;
        wxhi[rank] = -1e30f;
        wylo[rank] = 1e30f;
        wyhi[rank] = -1e30f;
    }
}

// ---------------- Kernel 2: per-pixel front-to-back (sorted order) composite ----------------
__global__ void __launch_bounds__(256)
render_kernel(const float* __restrict__ ws, float* __restrict__ out)
{
    __shared__ float sm[NFIELD * NG];
    for (int idx = threadIdx.x; idx < NFIELD * NG; idx += blockDim.x)
        sm[idx] = ws[idx];
    __syncthreads();

    const float* s_px  = sm + F_PX*NG;
    const float* s_py  = sm + F_PY*NG;
    const float* s_ia  = sm + F_IA*NG;
    const float* s_ib  = sm + F_IB*NG;
    const float* s_ic  = sm + F_IC*NG;
    const float* s_op  = sm + F_OP*NG;
    const float* s_cr  = sm + F_CR*NG;
    const float* s_cg  = sm + F_CG*NG;
    const float* s_cb  = sm + F_CB*NG;
    const float* s_z   = sm + F_Z*NG;
    const float* s_xlo = sm + F_XLO*NG;
    const float* s_xhi = sm + F_XHI*NG;
    const float* s_ylo = sm + F_YLO*NG;
    const float* s_yhi = sm + F_YHI*NG;

    const int p = blockIdx.x * blockDim.x + threadIdx.x;
    if (p >= IMG_H * IMG_W) return;
    const int yi = p / IMG_W;
    const int xi = p - yi * IMG_W;
    const float gx = (float)xi;
    const float gy = (float)yi;

    float T = 1.0f;
    float accR = 0.0f, accG = 0.0f, accB = 0.0f, accA = 0.0f;
    float depth = 0.0f;
    bool has = false;

    for (int i = 0; i < NG; ++i) {
        if (gx < s_xlo[i] || gx > s_xhi[i] || gy < s_ylo[i] || gy > s_yhi[i])
            continue;
        const float dx = gx - s_px[i];
        const float dy = gy - s_py[i];
        const float mahal = s_ia[i]*dx*dx + 2.0f*s_ib[i]*dx*dy + s_ic[i]*dy*dy;
        const float g = expf(-0.5f * mahal);
        float alpha = s_op[i] * g;
        alpha = fminf(fmaxf(alpha, 0.0f), 0.99f);
        const float w = alpha * T;
        accR += w * s_cr[i];
        accG += w * s_cg[i];
        accB += w * s_cb[i];
        accA += w;
        if (!has && w > 0.01f) { depth = s_z[i]; has = true; }
        T *= (1.0f - alpha);
    }

    float* rendered  = out;                          // [H,W,3]
    float* depth_map = out + IMG_H*IMG_W*3;          // [H,W]
    float* alpha_map = out + IMG_H*IMG_W*4;          // [H,W]

    rendered[3*p+0] = fminf(fmaxf(accR, 0.0f), 1.0f);
    rendered[3*p+1] = fminf(fmaxf(accG, 0.0f), 1.0f);
    rendered[3*p+2] = fminf(fmaxf(accB, 0.0f), 1.0f);
    depth_map[p] = has ? depth : 0.0f;
    alpha_map[p] = fminf(fmaxf(accA, 0.0f), 1.0f);
}

extern "C" void kernel_launch(void* const* d_in, const int* in_sizes, int n_in,
                              void* d_out, int out_size, void* d_ws, size_t ws_size,
                              hipStream_t stream) {
    const float* means  = (const float*)d_in[0];
    const float* scales = (const float*)d_in[1];
    const float* rots   = (const float*)d_in[2];
    const float* colors = (const float*)d_in[3];
    const float* opac   = (const float*)d_in[4];
    const float* Km     = (const float*)d_in[5];
    const float* Tm     = (const float*)d_in[6];
    float* out = (float*)d_out;
    float* ws  = (float*)d_ws;

    float* radii_out = out + IMG_H*IMG_W*5;   // rendered(3HW)+depth(HW)+alpha(HW)

    hipLaunchKernelGGL(prep_sort_kernel, dim3(1), dim3(NG), 0, stream,
                       means, scales, rots, colors, opac, Km, Tm, ws, radii_out);

    const int npix = IMG_H * IMG_W;
    hipLaunchKernelGGL(render_kernel, dim3((npix + 255) / 256), dim3(256), 0, stream,
                       ws, out);
}

// Round 2
// 93.420 us; speedup vs baseline: 1.7970x; 1.7970x over previous
//
#include <hip/hip_runtime.h>
#include <math.h>

#define IMG_H 240
#define IMG_W 320
#define NG 512
#define NEAR_P 0.1f
#define FAR_P 100.0f

#define TILE 16
#define TPB 256

// sorted SoA field offsets (each field is NG floats)
#define F_PX 0
#define F_PY 1
#define F_IA 2
#define F_IB 3
#define F_IC 4
#define F_OP 5
#define F_CR 6
#define F_CG 7
#define F_CB 8
#define F_Z  9
#define F_XLO 10
#define F_XHI 11
#define F_YLO 12
#define F_YHI 13
#define NFIELD 14

// ---------------- Kernel 1: preprocess + stable descending sort ----------------
__global__ void __launch_bounds__(NG)
prep_sort_kernel(const float* __restrict__ means,      // [NG,3]
                 const float* __restrict__ scales,     // [NG,3]
                 const float* __restrict__ rots,       // [NG,4]
                 const float* __restrict__ colors,     // [NG,3]
                 const float* __restrict__ opac,       // [NG]
                 const float* __restrict__ Km,         // [3,3]
                 const float* __restrict__ Tm,         // [4,4]
                 float* __restrict__ ws,               // [NFIELD*NG] sorted SoA
                 float* __restrict__ radii_out)        // [NG]
{
    const int i = threadIdx.x;

    const float fx = Km[0], fy = Km[4], cx = Km[2], cy = Km[5];
    const float Rc00 = Tm[0],  Rc01 = Tm[1],  Rc02 = Tm[2],  t0 = Tm[3];
    const float Rc10 = Tm[4],  Rc11 = Tm[5],  Rc12 = Tm[6],  t1 = Tm[7];
    const float Rc20 = Tm[8],  Rc21 = Tm[9],  Rc22 = Tm[10], t2 = Tm[11];

    const float mx = means[3*i+0], my = means[3*i+1], mz = means[3*i+2];
    const float xc = Rc00*mx + Rc01*my + Rc02*mz + t0;
    const float yc = Rc10*mx + Rc11*my + Rc12*mz + t1;
    const float zc = Rc20*mx + Rc21*my + Rc22*mz + t2;

    const float zs = (zc == 0.0f) ? 1e-8f : zc;
    const float px = fx * xc / zs + cx;
    const float py = fy * yc / zs + cy;

    // quaternion -> rotmat
    float qw = rots[4*i+0], qx = rots[4*i+1], qy = rots[4*i+2], qz = rots[4*i+3];
    const float qn = sqrtf(qw*qw + qx*qx + qy*qy + qz*qz);
    qw /= qn; qx /= qn; qy /= qn; qz /= qn;
    float R[3][3];
    R[0][0] = 1.0f - 2.0f*(qy*qy + qz*qz);
    R[0][1] = 2.0f*(qx*qy - qw*qz);
    R[0][2] = 2.0f*(qx*qz + qw*qy);
    R[1][0] = 2.0f*(qx*qy + qw*qz);
    R[1][1] = 1.0f - 2.0f*(qx*qx + qz*qz);
    R[1][2] = 2.0f*(qy*qz - qw*qx);
    R[2][0] = 2.0f*(qx*qz - qw*qy);
    R[2][1] = 2.0f*(qy*qz + qw*qx);
    R[2][2] = 1.0f - 2.0f*(qx*qx + qy*qy);

    const float s0 = scales[3*i+0], s1 = scales[3*i+1], s2v = scales[3*i+2];
    const float ss[3] = { s0*s0, s1*s1, s2v*s2v };

    float M[3][3];
    #pragma unroll
    for (int r = 0; r < 3; ++r)
        #pragma unroll
        for (int c = 0; c < 3; ++c)
            M[r][c] = R[r][0]*ss[0]*R[c][0] + R[r][1]*ss[1]*R[c][1] + R[r][2]*ss[2]*R[c][2];

    const float Rcm[3][3] = {{Rc00,Rc01,Rc02},{Rc10,Rc11,Rc12},{Rc20,Rc21,Rc22}};
    float A[3][3];
    #pragma unroll
    for (int r = 0; r < 3; ++r)
        #pragma unroll
        for (int c = 0; c < 3; ++c)
            A[r][c] = Rcm[r][0]*M[0][c] + Rcm[r][1]*M[1][c] + Rcm[r][2]*M[2][c];
    float V[3][3];
    #pragma unroll
    for (int r = 0; r < 3; ++r)
        #pragma unroll
        for (int c = 0; c < 3; ++c)
            V[r][c] = A[r][0]*Rcm[c][0] + A[r][1]*Rcm[c][1] + A[r][2]*Rcm[c][2];

    const float z2 = zs*zs;
    const float j00 = fx / zs, j02 = -fx * xc / z2;
    const float j11 = fy / zs, j12 = -fy * yc / z2;
    float P0[3], P1[3];
    #pragma unroll
    for (int c = 0; c < 3; ++c) {
        P0[c] = j00*V[0][c] + j02*V[2][c];
        P1[c] = j11*V[1][c] + j12*V[2][c];
    }
    const float a = P0[0]*j00 + P0[2]*j02;
    const float b = P0[1]*j11 + P0[2]*j12;
    const float c = P1[1]*j11 + P1[2]*j12;

    const float lam_max = 0.5f*(a + c) + sqrtf(fmaxf(0.25f*(a - c)*(a - c) + b*b, 0.0f));
    const float radius = 3.0f * sqrtf(fmaxf(lam_max, 0.0f));

    const bool visible = (zc > NEAR_P) && (zc < FAR_P) &&
                         (px >= 0.0f) && (px < (float)IMG_W) &&
                         (py >= 0.0f) && (py < (float)IMG_H);

    radii_out[i] = visible ? radius : 0.0f;

    // --- stable descending sort by key ---
    __shared__ float skey[NG];
    const float key = visible ? zc : -1e30f;
    skey[i] = key;
    __syncthreads();
    int rank = 0;
    #pragma unroll 8
    for (int j = 0; j < NG; ++j) {
        const float kj = skey[j];
        rank += (kj > key) || (kj == key && j < i);
    }

    const float eps = 1e-6f;
    const float ae = a + eps, ce = c + eps;
    const float det = ae*ce - b*b;
    const float ia = ce / det;
    const float ib = -b / det;
    const float ic = ae / det;

    const float cxp = floorf(px), cyp = floorf(py);
    const float r_int = floorf(radius) + 1.0f;

    ws[F_PX*NG + rank] = px;
    ws[F_PY*NG + rank] = py;
    ws[F_IA*NG + rank] = ia;
    ws[F_IB*NG + rank] = ib;
    ws[F_IC*NG + rank] = ic;
    ws[F_OP*NG + rank] = opac[i];
    ws[F_CR*NG + rank] = colors[3*i+0];
    ws[F_CG*NG + rank] = colors[3*i+1];
    ws[F_CB*NG + rank] = colors[3*i+2];
    ws[F_Z *NG + rank] = zc;
    if (visible) {
        ws[F_XLO*NG + rank] = cxp - r_int;
        ws[F_XHI*NG + rank] = cxp + r_int;
        ws[F_YLO*NG + rank] = cyp - r_int;
        ws[F_YHI*NG + rank] = cyp + r_int;
    } else {
        ws[F_XLO*NG + rank] = 1e30f;
        ws[F_XHI*NG + rank] = -1e30f;
        ws[F_YLO*NG + rank] = 1e30f;
        ws[F_YHI*NG + rank] = -1e30f;
    }
}

// ---------------- Kernel 2: tiled cull + stable compact + composite ----------------
// One block per 16x16 pixel tile. 256 threads.
__global__ void __launch_bounds__(TPB)
render_tiled_kernel(const float* __restrict__ ws, float* __restrict__ out)
{
    __shared__ float s_c[NFIELD * NG];   // compacted fields
    __shared__ int   s_wsum[TPB / 64];

    const int tid  = threadIdx.x;
    const int lane = tid & 63;
    const int wid  = tid >> 6;

    const int tiles_x = IMG_W / TILE;             // 20
    const int tile_id = blockIdx.x;
    const int tx0 = (tile_id % tiles_x) * TILE;
    const int ty0 = (tile_id / tiles_x) * TILE;
    const float ftx0 = (float)tx0, ftx1 = (float)(tx0 + TILE - 1);
    const float fty0 = (float)ty0, fty1 = (float)(ty0 + TILE - 1);

    // --- cull: 2 gaussians per thread, tile-overlap test on precomputed boxes ---
    const int g0 = 2 * tid, g1 = 2 * tid + 1;
    const float xlo0 = ws[F_XLO*NG + g0], xhi0 = ws[F_XHI*NG + g0];
    const float ylo0 = ws[F_YLO*NG + g0], yhi0 = ws[F_YHI*NG + g0];
    const float xlo1 = ws[F_XLO*NG + g1], xhi1 = ws[F_XHI*NG + g1];
    const float ylo1 = ws[F_YLO*NG + g1], yhi1 = ws[F_YHI*NG + g1];
    const int f0 = (xhi0 >= ftx0) && (xlo0 <= ftx1) && (yhi0 >= fty0) && (ylo0 <= fty1);
    const int f1 = (xhi1 >= ftx0) && (xlo1 <= ftx1) && (yhi1 >= fty0) && (ylo1 <= fty1);

    // --- stable prefix scan (wave shuffle + cross-wave offsets) ---
    int c = f0 + f1;
    #pragma unroll
    for (int d = 1; d < 64; d <<= 1) {
        int n = __shfl_up(c, d);
        if (lane >= d) c += n;
    }
    if (lane == 63) s_wsum[wid] = c;
    __syncthreads();
    int woff = 0;
    #pragma unroll
    for (int w = 0; w < TPB / 64; ++w)
        woff += (w < wid) ? s_wsum[w] : 0;
    const int excl = woff + c - (f0 + f1);
    const int p0 = excl;
    const int p1 = excl + f0;
    int M = 0;
    #pragma unroll
    for (int w = 0; w < TPB / 64; ++w) M += s_wsum[w];

    // --- gather survivors' fields into compact LDS arrays (order preserved) ---
    if (f0) {
        #pragma unroll
        for (int f = 0; f < NFIELD; ++f)
            s_c[f*NG + p0] = ws[f*NG + g0];
    }
    if (f1) {
        #pragma unroll
        for (int f = 0; f < NFIELD; ++f)
            s_c[f*NG + p1] = ws[f*NG + g1];
    }
    __syncthreads();

    // --- composite: one thread per pixel, loop over compacted list ---
    const int lx = tid & (TILE - 1);
    const int ly = tid / TILE;
    const int xi = tx0 + lx;
    const int yi = ty0 + ly;
    const float gx = (float)xi;
    const float gy = (float)yi;

    float T = 1.0f;
    float accR = 0.0f, accG = 0.0f, accB = 0.0f, accA = 0.0f;
    float depth = 0.0f;
    bool has = false;

    for (int i = 0; i < M; ++i) {
        if (gx < s_c[F_XLO*NG + i] || gx > s_c[F_XHI*NG + i] ||
            gy < s_c[F_YLO*NG + i] || gy > s_c[F_YHI*NG + i])
            continue;
        const float dx = gx - s_c[F_PX*NG + i];
        const float dy = gy - s_c[F_PY*NG + i];
        const float mahal = s_c[F_IA*NG + i]*dx*dx + 2.0f*s_c[F_IB*NG + i]*dx*dy
                          + s_c[F_IC*NG + i]*dy*dy;
        const float g = expf(-0.5f * mahal);
        float alpha = s_c[F_OP*NG + i] * g;
        alpha = fminf(fmaxf(alpha, 0.0f), 0.99f);
        const float w = alpha * T;
        accR += w * s_c[F_CR*NG + i];
        accG += w * s_c[F_CG*NG + i];
        accB += w * s_c[F_CB*NG + i];
        accA += w;
        if (!has && w > 0.01f) { depth = s_c[F_Z*NG + i]; has = true; }
        T *= (1.0f - alpha);
    }

    const int p = yi * IMG_W + xi;
    float* rendered  = out;                          // [H,W,3]
    float* depth_map = out + IMG_H*IMG_W*3;          // [H,W]
    float* alpha_map = out + IMG_H*IMG_W*4;          // [H,W]

    rendered[3*p+0] = fminf(fmaxf(accR, 0.0f), 1.0f);
    rendered[3*p+1] = fminf(fmaxf(accG, 0.0f), 1.0f);
    rendered[3*p+2] = fminf(fmaxf(accB, 0.0f), 1.0f);
    depth_map[p] = has ? depth : 0.0f;
    alpha_map[p] = fminf(fmaxf(accA, 0.0f), 1.0f);
}

extern "C" void kernel_launch(void* const* d_in, const int* in_sizes, int n_in,
                              void* d_out, int out_size, void* d_ws, size_t ws_size,
                              hipStream_t stream) {
    const float* means  = (const float*)d_in[0];
    const float* scales = (const float*)d_in[1];
    const float* rots   = (const float*)d_in[2];
    const float* colors = (const float*)d_in[3];
    const float* opac   = (const float*)d_in[4];
    const float* Km     = (const float*)d_in[5];
    const float* Tm     = (const float*)d_in[6];
    float* out = (float*)d_out;
    float* ws  = (float*)d_ws;

    float* radii_out = out + IMG_H*IMG_W*5;   // rendered(3HW)+depth(HW)+alpha(HW)

    hipLaunchKernelGGL(prep_sort_kernel, dim3(1), dim3(NG), 0, stream,
                       means, scales, rots, colors, opac, Km, Tm, ws, radii_out);

    const int ntiles = (IMG_W / TILE) * (IMG_H / TILE);   // 300
    hipLaunchKernelGGL(render_tiled_kernel, dim3(ntiles), dim3(TPB), 0, stream,
                       ws, out);
}

// Round 3
// 79.287 us; speedup vs baseline: 2.1174x; 1.1783x over previous
//
#include <hip/hip_runtime.h>
#include <math.h>

#define IMG_H 240
#define IMG_W 320
#define NG 512
#define NEAR_P 0.1f
#define FAR_P 100.0f

#define TILE 16
#define TPB 256

// compacted-survivor SoA field offsets (each field is NG floats)
#define F_PX 0
#define F_PY 1
#define F_IA 2
#define F_IB 3
#define F_IC 4
#define F_OP 5
#define F_CR 6
#define F_CG 7
#define F_CB 8
#define F_Z  9
#define F_XLO 10
#define F_XHI 11
#define F_YLO 12
#define F_YHI 13
#define NFIELD 14

struct GP {
    float px, py, ia, ib, ic, op, cr, cg, cb, z, xlo, xhi, ylo, yhi;
    int vis;
    float radius;
};

__device__ __forceinline__ GP prep_gaussian(
    int i,
    const float* __restrict__ means, const float* __restrict__ scales,
    const float* __restrict__ rots,  const float* __restrict__ colors,
    const float* __restrict__ opac,
    float fx, float fy, float cx, float cy,
    float Rc00, float Rc01, float Rc02, float t0,
    float Rc10, float Rc11, float Rc12, float t1,
    float Rc20, float Rc21, float Rc22, float t2)
{
    GP g;

    const float mx = means[3*i+0], my = means[3*i+1], mz = means[3*i+2];
    const float xc = Rc00*mx + Rc01*my + Rc02*mz + t0;
    const float yc = Rc10*mx + Rc11*my + Rc12*mz + t1;
    const float zc = Rc20*mx + Rc21*my + Rc22*mz + t2;

    const float zs = (zc == 0.0f) ? 1e-8f : zc;
    const float px = fx * xc / zs + cx;
    const float py = fy * yc / zs + cy;

    // quaternion -> rotmat
    float qw = rots[4*i+0], qx = rots[4*i+1], qy = rots[4*i+2], qz = rots[4*i+3];
    const float qn = sqrtf(qw*qw + qx*qx + qy*qy + qz*qz);
    qw /= qn; qx /= qn; qy /= qn; qz /= qn;
    float R[3][3];
    R[0][0] = 1.0f - 2.0f*(qy*qy + qz*qz);
    R[0][1] = 2.0f*(qx*qy - qw*qz);
    R[0][2] = 2.0f*(qx*qz + qw*qy);
    R[1][0] = 2.0f*(qx*qy + qw*qz);
    R[1][1] = 1.0f - 2.0f*(qx*qx + qz*qz);
    R[1][2] = 2.0f*(qy*qz - qw*qx);
    R[2][0] = 2.0f*(qx*qz - qw*qy);
    R[2][1] = 2.0f*(qy*qz + qw*qx);
    R[2][2] = 1.0f - 2.0f*(qx*qx + qy*qy);

    const float s0 = scales[3*i+0], s1 = scales[3*i+1], s2v = scales[3*i+2];
    const float ss[3] = { s0*s0, s1*s1, s2v*s2v };

    // cov3d M = R diag(ss) R^T
    float M3[3][3];
    #pragma unroll
    for (int r = 0; r < 3; ++r)
        #pragma unroll
        for (int c = 0; c < 3; ++c)
            M3[r][c] = R[r][0]*ss[0]*R[c][0] + R[r][1]*ss[1]*R[c][1] + R[r][2]*ss[2]*R[c][2];

    // V = Rc M Rc^T
    const float Rcm[3][3] = {{Rc00,Rc01,Rc02},{Rc10,Rc11,Rc12},{Rc20,Rc21,Rc22}};
    float A[3][3];
    #pragma unroll
    for (int r = 0; r < 3; ++r)
        #pragma unroll
        for (int c = 0; c < 3; ++c)
            A[r][c] = Rcm[r][0]*M3[0][c] + Rcm[r][1]*M3[1][c] + Rcm[r][2]*M3[2][c];
    float V[3][3];
    #pragma unroll
    for (int r = 0; r < 3; ++r)
        #pragma unroll
        for (int c = 0; c < 3; ++c)
            V[r][c] = A[r][0]*Rcm[c][0] + A[r][1]*Rcm[c][1] + A[r][2]*Rcm[c][2];

    const float z2 = zs*zs;
    const float j00 = fx / zs, j02 = -fx * xc / z2;
    const float j11 = fy / zs, j12 = -fy * yc / z2;
    float P0[3], P1[3];
    #pragma unroll
    for (int c = 0; c < 3; ++c) {
        P0[c] = j00*V[0][c] + j02*V[2][c];
        P1[c] = j11*V[1][c] + j12*V[2][c];
    }
    const float a = P0[0]*j00 + P0[2]*j02;
    const float b = P0[1]*j11 + P0[2]*j12;
    const float c = P1[1]*j11 + P1[2]*j12;

    const float lam_max = 0.5f*(a + c) + sqrtf(fmaxf(0.25f*(a - c)*(a - c) + b*b, 0.0f));
    const float radius = 3.0f * sqrtf(fmaxf(lam_max, 0.0f));

    const bool visible = (zc > NEAR_P) && (zc < FAR_P) &&
                         (px >= 0.0f) && (px < (float)IMG_W) &&
                         (py >= 0.0f) && (py < (float)IMG_H);

    const float eps = 1e-6f;
    const float ae = a + eps, ce = c + eps;
    const float det = ae*ce - b*b;

    g.px = px; g.py = py;
    g.ia = ce / det; g.ib = -b / det; g.ic = ae / det;
    g.op = opac[i];
    g.cr = colors[3*i+0]; g.cg = colors[3*i+1]; g.cb = colors[3*i+2];
    g.z = zc;
    const float cxp = floorf(px), cyp = floorf(py);
    const float r_int = floorf(radius) + 1.0f;
    g.xlo = cxp - r_int; g.xhi = cxp + r_int;
    g.ylo = cyp - r_int; g.yhi = cyp + r_int;
    g.vis = visible ? 1 : 0;
    g.radius = radius;
    return g;
}

// ---------------- fused kernel: prep + cull + stable compact + sort + composite ----------------
// One block per 16x16 pixel tile. 256 threads, 2 gaussians/thread.
__global__ void __launch_bounds__(TPB)
fused_render_kernel(const float* __restrict__ means,
                    const float* __restrict__ scales,
                    const float* __restrict__ rots,
                    const float* __restrict__ colors,
                    const float* __restrict__ opac,
                    const float* __restrict__ Km,
                    const float* __restrict__ Tm,
                    float* __restrict__ out)
{
    __shared__ float s_f[NFIELD * NG];
    __shared__ int   s_wsum[TPB / 64];

    const int tid  = threadIdx.x;
    const int lane = tid & 63;
    const int wid  = tid >> 6;

    const float fx = Km[0], fy = Km[4], cx = Km[2], cy = Km[5];
    const float Rc00 = Tm[0],  Rc01 = Tm[1],  Rc02 = Tm[2],  t0 = Tm[3];
    const float Rc10 = Tm[4],  Rc11 = Tm[5],  Rc12 = Tm[6],  t1 = Tm[7];
    const float Rc20 = Tm[8],  Rc21 = Tm[9],  Rc22 = Tm[10], t2 = Tm[11];

    const int tiles_x = IMG_W / TILE;             // 20
    const int tile_id = blockIdx.x;
    const int tx0 = (tile_id % tiles_x) * TILE;
    const int ty0 = (tile_id / tiles_x) * TILE;
    const float ftx0 = (float)tx0, ftx1 = (float)(tx0 + TILE - 1);
    const float fty0 = (float)ty0, fty1 = (float)(ty0 + TILE - 1);

    // --- prep 2 gaussians per thread (registers only) ---
    const int g0 = 2 * tid, g1 = 2 * tid + 1;
    GP p0 = prep_gaussian(g0, means, scales, rots, colors, opac, fx, fy, cx, cy,
                          Rc00, Rc01, Rc02, t0, Rc10, Rc11, Rc12, t1, Rc20, Rc21, Rc22, t2);
    GP p1 = prep_gaussian(g1, means, scales, rots, colors, opac, fx, fy, cx, cy,
                          Rc00, Rc01, Rc02, t0, Rc10, Rc11, Rc12, t1, Rc20, Rc21, Rc22, t2);

    if (tile_id == 0) {
        float* radii_out = out + IMG_H*IMG_W*5;
        radii_out[g0] = p0.vis ? p0.radius : 0.0f;
        radii_out[g1] = p1.vis ? p1.radius : 0.0f;
    }

    // --- cull against tile (visible && box overlaps tile) ---
    const int f0 = p0.vis && (p0.xhi >= ftx0) && (p0.xlo <= ftx1) && (p0.yhi >= fty0) && (p0.ylo <= fty1);
    const int f1 = p1.vis && (p1.xhi >= ftx0) && (p1.xlo <= ftx1) && (p1.yhi >= fty0) && (p1.ylo <= fty1);

    // --- stable prefix scan (wave shuffle + cross-wave offsets) ---
    int c = f0 + f1;
    #pragma unroll
    for (int d = 1; d < 64; d <<= 1) {
        int n = __shfl_up(c, d);
        if (lane >= d) c += n;
    }
    if (lane == 63) s_wsum[wid] = c;
    __syncthreads();
    int woff = 0;
    #pragma unroll
    for (int w = 0; w < TPB / 64; ++w)
        woff += (w < wid) ? s_wsum[w] : 0;
    const int excl = woff + c - (f0 + f1);
    const int q0 = excl;
    const int q1 = excl + f0;
    int M = 0;
    #pragma unroll
    for (int w = 0; w < TPB / 64; ++w) M += s_wsum[w];

    // --- write survivors to compacted LDS slots (original index order preserved) ---
    if (f0) {
        s_f[F_PX*NG + q0] = p0.px;  s_f[F_PY*NG + q0] = p0.py;
        s_f[F_IA*NG + q0] = p0.ia;  s_f[F_IB*NG + q0] = p0.ib;  s_f[F_IC*NG + q0] = p0.ic;
        s_f[F_OP*NG + q0] = p0.op;
        s_f[F_CR*NG + q0] = p0.cr;  s_f[F_CG*NG + q0] = p0.cg;  s_f[F_CB*NG + q0] = p0.cb;
        s_f[F_Z *NG + q0] = p0.z;
        s_f[F_XLO*NG + q0] = p0.xlo; s_f[F_XHI*NG + q0] = p0.xhi;
        s_f[F_YLO*NG + q0] = p0.ylo; s_f[F_YHI*NG + q0] = p0.yhi;
    }
    if (f1) {
        s_f[F_PX*NG + q1] = p1.px;  s_f[F_PY*NG + q1] = p1.py;
        s_f[F_IA*NG + q1] = p1.ia;  s_f[F_IB*NG + q1] = p1.ib;  s_f[F_IC*NG + q1] = p1.ic;
        s_f[F_OP*NG + q1] = p1.op;
        s_f[F_CR*NG + q1] = p1.cr;  s_f[F_CG*NG + q1] = p1.cg;  s_f[F_CB*NG + q1] = p1.cb;
        s_f[F_Z *NG + q1] = p1.z;
        s_f[F_XLO*NG + q1] = p1.xlo; s_f[F_XHI*NG + q1] = p1.xhi;
        s_f[F_YLO*NG + q1] = p1.ylo; s_f[F_YHI*NG + q1] = p1.yhi;
    }
    __syncthreads();

    // --- stable descending-z rank sort of the M survivors, in place ---
    // each thread owns slots tid and tid+TPB; stage fields in regs, then scatter.
    float regs[2][NFIELD];
    int   rnk[2];
    #pragma unroll
    for (int s = 0; s < 2; ++s) {
        const int slot = tid + s * TPB;
        rnk[s] = -1;
        if (slot < M) {
            const float key = s_f[F_Z*NG + slot];
            int r = 0;
            for (int j = 0; j < M; ++j) {
                const float kj = s_f[F_Z*NG + j];
                r += (kj > key) || (kj == key && j < slot);
            }
            rnk[s] = r;
            #pragma unroll
            for (int f = 0; f < NFIELD; ++f)
                regs[s][f] = s_f[f*NG + slot];
        }
    }
    __syncthreads();
    #pragma unroll
    for (int s = 0; s < 2; ++s) {
        if (rnk[s] >= 0) {
            #pragma unroll
            for (int f = 0; f < NFIELD; ++f)
                s_f[f*NG + rnk[s]] = regs[s][f];
        }
    }
    __syncthreads();

    // --- composite: one thread per pixel, loop over sorted compacted list ---
    const int lx = tid & (TILE - 1);
    const int ly = tid / TILE;
    const int xi = tx0 + lx;
    const int yi = ty0 + ly;
    const float gx = (float)xi;
    const float gy = (float)yi;

    float T = 1.0f;
    float accR = 0.0f, accG = 0.0f, accB = 0.0f, accA = 0.0f;
    float depth = 0.0f;
    bool has = false;

    for (int i = 0; i < M; ++i) {
        if (gx < s_f[F_XLO*NG + i] || gx > s_f[F_XHI*NG + i] ||
            gy < s_f[F_YLO*NG + i] || gy > s_f[F_YHI*NG + i])
            continue;
        const float dx = gx - s_f[F_PX*NG + i];
        const float dy = gy - s_f[F_PY*NG + i];
        const float mahal = s_f[F_IA*NG + i]*dx*dx + 2.0f*s_f[F_IB*NG + i]*dx*dy
                          + s_f[F_IC*NG + i]*dy*dy;
        const float g = expf(-0.5f * mahal);
        float alpha = s_f[F_OP*NG + i] * g;
        alpha = fminf(fmaxf(alpha, 0.0f), 0.99f);
        const float w = alpha * T;
        accR += w * s_f[F_CR*NG + i];
        accG += w * s_f[F_CG*NG + i];
        accB += w * s_f[F_CB*NG + i];
        accA += w;
        if (!has && w > 0.01f) { depth = s_f[F_Z*NG + i]; has = true; }
        T *= (1.0f - alpha);
    }

    const int p = yi * IMG_W + xi;
    float* rendered  = out;                          // [H,W,3]
    float* depth_map = out + IMG_H*IMG_W*3;          // [H,W]
    float* alpha_map = out + IMG_H*IMG_W*4;          // [H,W]

    rendered[3*p+0] = fminf(fmaxf(accR, 0.0f), 1.0f);
    rendered[3*p+1] = fminf(fmaxf(accG, 0.0f), 1.0f);
    rendered[3*p+2] = fminf(fmaxf(accB, 0.0f), 1.0f);
    depth_map[p] = has ? depth : 0.0f;
    alpha_map[p] = fminf(fmaxf(accA, 0.0f), 1.0f);
}

extern "C" void kernel_launch(void* const* d_in, const int* in_sizes, int n_in,
                              void* d_out, int out_size, void* d_ws, size_t ws_size,
                              hipStream_t stream) {
    const float* means  = (const float*)d_in[0];
    const float* scales = (const float*)d_in[1];
    const float* rots   = (const float*)d_in[2];
    const float* colors = (const float*)d_in[3];
    const float* opac   = (const float*)d_in[4];
    const float* Km     = (const float*)d_in[5];
    const float* Tm     = (const float*)d_in[6];
    float* out = (float*)d_out;
    (void)d_ws; (void)ws_size;

    const int ntiles = (IMG_W / TILE) * (IMG_H / TILE);   // 300
    hipLaunchKernelGGL(fused_render_kernel, dim3(ntiles), dim3(TPB), 0, stream,
                       means, scales, rots, colors, opac, Km, Tm, out);
}

// Round 4
// 77.266 us; speedup vs baseline: 2.1727x; 1.0262x over previous
//
#include <hip/hip_runtime.h>
#include <math.h>

#define IMG_H 240
#define IMG_W 320
#define NG 512
#define NEAR_P 0.1f
#define FAR_P 100.0f

#define TILE 16
#define TPB 256

struct GP {
    float px, py, ia, ib, ic, op, cr, cg, cb, z, xlo, xhi, ylo, yhi, radius;
    int vis;
};

__device__ __forceinline__ float fast_rcp(float x) { return __builtin_amdgcn_rcpf(x); }
__device__ __forceinline__ float fast_rsq(float x) { return __builtin_amdgcn_rsqf(x); }

__device__ __forceinline__ GP prep_gaussian(
    int i,
    const float* __restrict__ means, const float* __restrict__ scales,
    const float* __restrict__ rots,  const float* __restrict__ colors,
    const float* __restrict__ opac,
    float fx, float fy, float cx, float cy,
    float Rc00, float Rc01, float Rc02, float t0,
    float Rc10, float Rc11, float Rc12, float t1,
    float Rc20, float Rc21, float Rc22, float t2)
{
    GP g;

    const float mx = means[3*i+0], my = means[3*i+1], mz = means[3*i+2];
    const float xc = Rc00*mx + Rc01*my + Rc02*mz + t0;
    const float yc = Rc10*mx + Rc11*my + Rc12*mz + t1;
    const float zc = Rc20*mx + Rc21*my + Rc22*mz + t2;

    const float zs = (zc == 0.0f) ? 1e-8f : zc;
    const float iz = fast_rcp(zs);
    const float px = fx * xc * iz + cx;
    const float py = fy * yc * iz + cy;

    // quaternion -> rotmat (rsq-normalized)
    float qw = rots[4*i+0], qx = rots[4*i+1], qy = rots[4*i+2], qz = rots[4*i+3];
    const float iqn = fast_rsq(qw*qw + qx*qx + qy*qy + qz*qz);
    qw *= iqn; qx *= iqn; qy *= iqn; qz *= iqn;
    float R[3][3];
    R[0][0] = 1.0f - 2.0f*(qy*qy + qz*qz);
    R[0][1] = 2.0f*(qx*qy - qw*qz);
    R[0][2] = 2.0f*(qx*qz + qw*qy);
    R[1][0] = 2.0f*(qx*qy + qw*qz);
    R[1][1] = 1.0f - 2.0f*(qx*qx + qz*qz);
    R[1][2] = 2.0f*(qy*qz - qw*qx);
    R[2][0] = 2.0f*(qx*qz - qw*qy);
    R[2][1] = 2.0f*(qy*qz + qw*qx);
    R[2][2] = 1.0f - 2.0f*(qx*qx + qy*qy);

    const float s0 = scales[3*i+0], s1 = scales[3*i+1], s2v = scales[3*i+2];
    const float ss[3] = { s0*s0, s1*s1, s2v*s2v };

    // cov3d M = R diag(ss) R^T
    float M3[3][3];
    #pragma unroll
    for (int r = 0; r < 3; ++r)
        #pragma unroll
        for (int c = 0; c < 3; ++c)
            M3[r][c] = R[r][0]*ss[0]*R[c][0] + R[r][1]*ss[1]*R[c][1] + R[r][2]*ss[2]*R[c][2];

    // V = Rc M Rc^T
    const float Rcm[3][3] = {{Rc00,Rc01,Rc02},{Rc10,Rc11,Rc12},{Rc20,Rc21,Rc22}};
    float A[3][3];
    #pragma unroll
    for (int r = 0; r < 3; ++r)
        #pragma unroll
        for (int c = 0; c < 3; ++c)
            A[r][c] = Rcm[r][0]*M3[0][c] + Rcm[r][1]*M3[1][c] + Rcm[r][2]*M3[2][c];
    float V[3][3];
    #pragma unroll
    for (int r = 0; r < 3; ++r)
        #pragma unroll
        for (int c = 0; c < 3; ++c)
            V[r][c] = A[r][0]*Rcm[c][0] + A[r][1]*Rcm[c][1] + A[r][2]*Rcm[c][2];

    const float j00 = fx * iz, j02 = -fx * xc * iz * iz;
    const float j11 = fy * iz, j12 = -fy * yc * iz * iz;
    float P0[3], P1[3];
    #pragma unroll
    for (int c = 0; c < 3; ++c) {
        P0[c] = j00*V[0][c] + j02*V[2][c];
        P1[c] = j11*V[1][c] + j12*V[2][c];
    }
    const float a = P0[0]*j00 + P0[2]*j02;
    const float b = P0[1]*j11 + P0[2]*j12;
    const float c = P1[1]*j11 + P1[2]*j12;

    const float lam_max = 0.5f*(a + c) + sqrtf(fmaxf(0.25f*(a - c)*(a - c) + b*b, 0.0f));
    const float radius = 3.0f * sqrtf(fmaxf(lam_max, 0.0f));

    const bool visible = (zc > NEAR_P) && (zc < FAR_P) &&
                         (px >= 0.0f) && (px < (float)IMG_W) &&
                         (py >= 0.0f) && (py < (float)IMG_H);

    const float eps = 1e-6f;
    const float ae = a + eps, ce = c + eps;
    const float det = ae*ce - b*b;
    const float idet = fast_rcp(det);

    g.px = px; g.py = py;
    g.ia = ce * idet; g.ib = -b * idet; g.ic = ae * idet;
    g.op = opac[i];
    g.cr = colors[3*i+0]; g.cg = colors[3*i+1]; g.cb = colors[3*i+2];
    g.z = zc;
    const float cxp = floorf(px), cyp = floorf(py);
    const float r_int = floorf(radius) + 1.0f;
    g.xlo = cxp - r_int; g.xhi = cxp + r_int;
    g.ylo = cyp - r_int; g.yhi = cyp + r_int;
    g.vis = visible ? 1 : 0;
    g.radius = radius;
    return g;
}

// ---------------- fused: prep + tile-cull + stable compact + rank-sort + composite ----------------
// One block per 16x16 tile. 256 threads, 2 gaussians/thread.
__global__ void __launch_bounds__(TPB)
fused_render_kernel(const float* __restrict__ means,
                    const float* __restrict__ scales,
                    const float* __restrict__ rots,
                    const float* __restrict__ colors,
                    const float* __restrict__ opac,
                    const float* __restrict__ Km,
                    const float* __restrict__ Tm,
                    float* __restrict__ out)
{
    // AoS: 4 float4 rows per sorted survivor:
    // row0 = {xlo,xhi,ylo,yhi}  row1 = {px,py,ia,ib}  row2 = {ic,op,z,cr}  row3 = {cg,cb,-,-}
    __shared__ float4 s_g[NG * 4];
    __shared__ float  s_zkey[NG];
    __shared__ int    s_wsum[TPB / 64];

    const int tid  = threadIdx.x;
    const int lane = tid & 63;
    const int wid  = tid >> 6;

    const float fx = Km[0], fy = Km[4], cx = Km[2], cy = Km[5];
    const float Rc00 = Tm[0],  Rc01 = Tm[1],  Rc02 = Tm[2],  t0 = Tm[3];
    const float Rc10 = Tm[4],  Rc11 = Tm[5],  Rc12 = Tm[6],  t1 = Tm[7];
    const float Rc20 = Tm[8],  Rc21 = Tm[9],  Rc22 = Tm[10], t2 = Tm[11];

    const int tiles_x = IMG_W / TILE;             // 20
    const int tile_id = blockIdx.x;
    const int tx0 = (tile_id % tiles_x) * TILE;
    const int ty0 = (tile_id / tiles_x) * TILE;
    const float ftx0 = (float)tx0, ftx1 = (float)(tx0 + TILE - 1);
    const float fty0 = (float)ty0, fty1 = (float)(ty0 + TILE - 1);

    // --- prep 2 gaussians per thread (registers only) ---
    const int g0 = 2 * tid, g1 = 2 * tid + 1;
    GP p0 = prep_gaussian(g0, means, scales, rots, colors, opac, fx, fy, cx, cy,
                          Rc00, Rc01, Rc02, t0, Rc10, Rc11, Rc12, t1, Rc20, Rc21, Rc22, t2);
    GP p1 = prep_gaussian(g1, means, scales, rots, colors, opac, fx, fy, cx, cy,
                          Rc00, Rc01, Rc02, t0, Rc10, Rc11, Rc12, t1, Rc20, Rc21, Rc22, t2);

    if (tile_id == 0) {
        float* radii_out = out + IMG_H*IMG_W*5;
        radii_out[g0] = p0.vis ? p0.radius : 0.0f;
        radii_out[g1] = p1.vis ? p1.radius : 0.0f;
    }

    // --- cull against tile ---
    const int f0 = p0.vis && (p0.xhi >= ftx0) && (p0.xlo <= ftx1) && (p0.yhi >= fty0) && (p0.ylo <= fty1);
    const int f1 = p1.vis && (p1.xhi >= ftx0) && (p1.xlo <= ftx1) && (p1.yhi >= fty0) && (p1.ylo <= fty1);

    // --- stable prefix scan (wave shuffle + cross-wave offsets) ---
    int c = f0 + f1;
    #pragma unroll
    for (int d = 1; d < 64; d <<= 1) {
        int n = __shfl_up(c, d);
        if (lane >= d) c += n;
    }
    if (lane == 63) s_wsum[wid] = c;
    __syncthreads();
    int woff = 0;
    #pragma unroll
    for (int w = 0; w < TPB / 64; ++w)
        woff += (w < wid) ? s_wsum[w] : 0;
    const int excl = woff + c - (f0 + f1);
    const int q0 = excl;          // compact position == original-index order rank
    const int q1 = excl + f0;
    int M = 0;
    #pragma unroll
    for (int w = 0; w < TPB / 64; ++w) M += s_wsum[w];

    // --- write z keys at compact positions ---
    if (f0) s_zkey[q0] = p0.z;
    if (f1) s_zkey[q1] = p1.z;
    __syncthreads();

    // --- rank among survivors (descending z, stable by compact position) and
    //     write full AoS row directly into the sorted slot ---
    if (f0) {
        const float key = p0.z;
        int r = 0;
        for (int j = 0; j < M; ++j) {
            const float kj = s_zkey[j];
            r += (kj > key) || (kj == key && j < q0);
        }
        s_g[4*r+0] = make_float4(p0.xlo, p0.xhi, p0.ylo, p0.yhi);
        s_g[4*r+1] = make_float4(p0.px,  p0.py,  p0.ia,  p0.ib);
        s_g[4*r+2] = make_float4(p0.ic,  p0.op,  p0.z,   p0.cr);
        s_g[4*r+3] = make_float4(p0.cg,  p0.cb,  0.0f,   0.0f);
    }
    if (f1) {
        const float key = p1.z;
        int r = 0;
        for (int j = 0; j < M; ++j) {
            const float kj = s_zkey[j];
            r += (kj > key) || (kj == key && j < q1);
        }
        s_g[4*r+0] = make_float4(p1.xlo, p1.xhi, p1.ylo, p1.yhi);
        s_g[4*r+1] = make_float4(p1.px,  p1.py,  p1.ia,  p1.ib);
        s_g[4*r+2] = make_float4(p1.ic,  p1.op,  p1.z,   p1.cr);
        s_g[4*r+3] = make_float4(p1.cg,  p1.cb,  0.0f,   0.0f);
    }
    __syncthreads();

    // --- composite: one thread per pixel, sorted compacted list, b128 broadcasts ---
    const int lx = tid & (TILE - 1);
    const int ly = tid / TILE;
    const int xi = tx0 + lx;
    const int yi = ty0 + ly;
    const float gx = (float)xi;
    const float gy = (float)yi;

    float T = 1.0f;
    float accR = 0.0f, accG = 0.0f, accB = 0.0f, accA = 0.0f;
    float depth = 0.0f;
    bool has = false;

    for (int i = 0; i < M; ++i) {
        const float4 box = s_g[4*i+0];
        if (gx >= box.x && gx <= box.y && gy >= box.z && gy <= box.w) {
            const float4 r1 = s_g[4*i+1];
            const float4 r2 = s_g[4*i+2];
            const float4 r3 = s_g[4*i+3];
            const float dx = gx - r1.x;
            const float dy = gy - r1.y;
            const float mahal = r1.z*dx*dx + 2.0f*r1.w*dx*dy + r2.x*dy*dy;
            const float g = __expf(-0.5f * mahal);
            const float alpha = fminf(r2.y * g, 0.99f);   // op*g >= 0 always
            const float w = alpha * T;
            accR += w * r2.w;
            accG += w * r3.x;
            accB += w * r3.y;
            accA += w;
            if (!has && w > 0.01f) { depth = r2.z; has = true; }
            T *= (1.0f - alpha);
            // future contributions bounded by T: color/alpha error <= 1e-4,
            // and future w < 1e-4 < 0.01 can never set depth -> safe early out.
            if (T < 1e-4f) break;
        }
    }

    const int p = yi * IMG_W + xi;
    float* rendered  = out;                          // [H,W,3]
    float* depth_map = out + IMG_H*IMG_W*3;          // [H,W]
    float* alpha_map = out + IMG_H*IMG_W*4;          // [H,W]

    rendered[3*p+0] = fminf(fmaxf(accR, 0.0f), 1.0f);
    rendered[3*p+1] = fminf(fmaxf(accG, 0.0f), 1.0f);
    rendered[3*p+2] = fminf(fmaxf(accB, 0.0f), 1.0f);
    depth_map[p] = has ? depth : 0.0f;
    alpha_map[p] = fminf(fmaxf(accA, 0.0f), 1.0f);
}

extern "C" void kernel_launch(void* const* d_in, const int* in_sizes, int n_in,
                              void* d_out, int out_size, void* d_ws, size_t ws_size,
                              hipStream_t stream) {
    const float* means  = (const float*)d_in[0];
    const float* scales = (const float*)d_in[1];
    const float* rots   = (const float*)d_in[2];
    const float* colors = (const float*)d_in[3];
    const float* opac   = (const float*)d_in[4];
    const float* Km     = (const float*)d_in[5];
    const float* Tm     = (const float*)d_in[6];
    float* out = (float*)d_out;
    (void)d_ws; (void)ws_size;

    const int ntiles = (IMG_W / TILE) * (IMG_H / TILE);   // 300
    hipLaunchKernelGGL(fused_render_kernel, dim3(ntiles), dim3(TPB), 0, stream,
                       means, scales, rots, colors, opac, Km, Tm, out);
}